// Round 1
// baseline (632.694 us; speedup 1.0000x reference)
//
#include <hip/hip_runtime.h>

#define BATCH   128
#define NUM_IN  4096
#define LVL     8
#define HID     32768
#define KH      32
#define OUTN    256
#define KOUT    64
#define SCALEA  4.9f

// ---------------------------------------------------------------------------
// Transpose x [B, NUM_IN] (b-major) -> act [node, b] (node-major, b contiguous)
// so that batch gathers for a shared index are coalesced.
// ---------------------------------------------------------------------------
__global__ __launch_bounds__(256) void transpose_x(const float* __restrict__ x,
                                                   float* __restrict__ act) {
    __shared__ float lds[64][129];   // +1 pad: conflict-free both phases
    const int n0 = blockIdx.x * 64;
    const int t  = threadIdx.x;
    #pragma unroll
    for (int it = 0; it < 32; ++it) {
        int i = it * 256 + t;
        int b = i >> 6;          // 0..127
        int n = i & 63;          // 0..63
        lds[n][b] = x[b * NUM_IN + n0 + n];   // coalesced 64-float row segments
    }
    __syncthreads();
    #pragma unroll
    for (int it = 0; it < 32; ++it) {
        int i = it * 256 + t;
        int n = i >> 7;          // 0..63
        int b = i & 127;         // 0..127
        act[(n0 + n) * BATCH + b] = lds[n][b];   // coalesced writes
    }
}

// ---------------------------------------------------------------------------
// One hidden level: one wave per hidden unit. idx/w are wave-uniform
// (readfirstlane -> scalar address math); each lane owns 2 batch elements
// (float2), so each (h,k) gather is one contiguous 512B wave read.
// ---------------------------------------------------------------------------
__global__ __launch_bounds__(256) void hidden_level(float* __restrict__ act,
                                                    const int* __restrict__ idx,
                                                    const float* __restrict__ w,
                                                    int base) {
    const int lane = threadIdx.x & 63;
    int h = (blockIdx.x << 2) + (threadIdx.x >> 6);
    h = __builtin_amdgcn_readfirstlane(h);
    const int*   ip = idx + h * KH;
    const float* wp = w   + h * KH;
    const int boff = lane * 2;

    float ax = 0.f, ay = 0.f;
    #pragma unroll
    for (int k = 0; k < KH; ++k) {
        int   j  = __builtin_amdgcn_readfirstlane(ip[k]);
        float wk = wp[k];
        const float2 v = *(const float2*)(act + (unsigned)j * BATCH + boff);
        ax = fmaf(wk, v.x, ax);
        ay = fmaf(wk, v.y, ay);
    }
    float2 r;
    r.x = 1.f / (1.f + __expf(-SCALEA * ax));
    r.y = 1.f / (1.f + __expf(-SCALEA * ay));
    *(float2*)(act + (unsigned)(base + h) * BATCH + boff) = r;
}

// ---------------------------------------------------------------------------
// Output layer: one wave per output unit, KO=64 fan-in. Writes to d_out in
// reference layout out[b][o] (b-major). Scattered stores, but only 128 KB.
// ---------------------------------------------------------------------------
__global__ __launch_bounds__(256) void output_layer(const float* __restrict__ act,
                                                    const int* __restrict__ idx,
                                                    const float* __restrict__ w,
                                                    float* __restrict__ out) {
    const int lane = threadIdx.x & 63;
    int o = (blockIdx.x << 2) + (threadIdx.x >> 6);
    o = __builtin_amdgcn_readfirstlane(o);
    const int*   ip = idx + o * KOUT;
    const float* wp = w   + o * KOUT;
    const int boff = lane * 2;

    float ax = 0.f, ay = 0.f;
    #pragma unroll
    for (int k = 0; k < KOUT; ++k) {
        int   j  = __builtin_amdgcn_readfirstlane(ip[k]);
        float wk = wp[k];
        const float2 v = *(const float2*)(act + (unsigned)j * BATCH + boff);
        ax = fmaf(wk, v.x, ax);
        ay = fmaf(wk, v.y, ay);
    }
    out[(boff + 0) * OUTN + o] = 1.f / (1.f + __expf(-SCALEA * ax));
    out[(boff + 1) * OUTN + o] = 1.f / (1.f + __expf(-SCALEA * ay));
}

extern "C" void kernel_launch(void* const* d_in, const int* in_sizes, int n_in,
                              void* d_out, int out_size, void* d_ws, size_t ws_size,
                              hipStream_t stream) {
    // setup_inputs() order: x, w_hidden, w_out, idx_hidden, idx_out
    const float* x          = (const float*)d_in[0];
    const float* w_hidden   = (const float*)d_in[1];
    const float* w_out      = (const float*)d_in[2];
    const int*   idx_hidden = (const int*)  d_in[3];
    const int*   idx_out    = (const int*)  d_in[4];
    float* out = (float*)d_out;

    // Activation buffer: (NUM_IN + L*H) nodes x 128 batch, node-major.
    // (4096 + 262144) * 128 * 4B = 136.3 MB in d_ws.
    float* act = (float*)d_ws;

    transpose_x<<<NUM_IN / 64, 256, 0, stream>>>(x, act);

    for (int l = 0; l < LVL; ++l) {
        hidden_level<<<HID / 4, 256, 0, stream>>>(
            act,
            idx_hidden + (size_t)l * HID * KH,
            w_hidden   + (size_t)l * HID * KH,
            NUM_IN + l * HID);
    }

    output_layer<<<OUTN / 4, 256, 0, stream>>>(act, idx_out, w_out, out);
}

// Round 2
// 362.927 us; speedup vs baseline: 1.7433x; 1.7433x over previous
//
#include <hip/hip_runtime.h>

#define BATCH   128
#define NUM_IN  4096
#define LVL     8
#define HID     32768
#define KH      32
#define OUTN    256
#define KOUT    64
#define SCALEA  4.9f

// act is stored node-major as bf16: act[node][b], 2B each, 256B per node.
// Viewed as uint: 64 uints per node, lane i holds batch {2i, 2i+1}.

__device__ __forceinline__ unsigned short f2bf(float f) {
    unsigned u = __float_as_uint(f);
    u += 0x7FFFu + ((u >> 16) & 1u);   // round-to-nearest-even
    return (unsigned short)(u >> 16);
}
__device__ __forceinline__ float bf_lo(unsigned u) { return __uint_as_float(u << 16); }
__device__ __forceinline__ float bf_hi(unsigned u) { return __uint_as_float(u & 0xFFFF0000u); }

// ---------------------------------------------------------------------------
// Transpose x [B, NUM_IN] f32 -> act [node][b] bf16 (packed pairs as uint)
// ---------------------------------------------------------------------------
__global__ __launch_bounds__(256) void transpose_x(const float* __restrict__ x,
                                                   unsigned* __restrict__ actu) {
    __shared__ float lds[64][129];
    const int n0 = blockIdx.x * 64;
    const int t  = threadIdx.x;
    #pragma unroll
    for (int it = 0; it < 32; ++it) {
        int i = it * 256 + t;
        int b = i >> 6;
        int n = i & 63;
        lds[n][b] = x[b * NUM_IN + n0 + n];
    }
    __syncthreads();
    #pragma unroll
    for (int it = 0; it < 16; ++it) {
        int i  = it * 256 + t;      // 0..4095 : 64 nodes x 64 uint-pairs
        int n  = i >> 6;
        int bp = i & 63;
        unsigned lo = f2bf(lds[n][2 * bp]);
        unsigned hi = f2bf(lds[n][2 * bp + 1]);
        actu[(n0 + n) * 64 + bp] = lo | (hi << 16);
    }
}

// ---------------------------------------------------------------------------
// One hidden level: one wave per hidden unit; wave-uniform idx/w; each lane
// owns 2 batch elements packed in one uint (256B coalesced gather per (h,k)).
// ---------------------------------------------------------------------------
__global__ __launch_bounds__(256) void hidden_level(unsigned* __restrict__ actu,
                                                    const int* __restrict__ idx,
                                                    const float* __restrict__ w,
                                                    int base) {
    const int lane = threadIdx.x & 63;
    int h = (blockIdx.x << 2) + (threadIdx.x >> 6);
    h = __builtin_amdgcn_readfirstlane(h);
    const int*   ip = idx + h * KH;
    const float* wp = w   + h * KH;

    float ax = 0.f, ay = 0.f;
    #pragma unroll
    for (int k = 0; k < KH; ++k) {
        int   j  = __builtin_amdgcn_readfirstlane(ip[k]);
        float wk = wp[k];
        unsigned u = actu[(unsigned)j * 64 + lane];
        ax = fmaf(wk, bf_lo(u), ax);
        ay = fmaf(wk, bf_hi(u), ay);
    }
    float rx = 1.f / (1.f + __expf(-SCALEA * ax));
    float ry = 1.f / (1.f + __expf(-SCALEA * ay));
    unsigned lo = f2bf(rx), hi = f2bf(ry);
    actu[(unsigned)(base + h) * 64 + lane] = lo | (hi << 16);
}

// ---------------------------------------------------------------------------
// Output layer: one wave per output unit, KO=64; f32 output in out[b][o].
// ---------------------------------------------------------------------------
__global__ __launch_bounds__(256) void output_layer(const unsigned* __restrict__ actu,
                                                    const int* __restrict__ idx,
                                                    const float* __restrict__ w,
                                                    float* __restrict__ out) {
    const int lane = threadIdx.x & 63;
    int o = (blockIdx.x << 2) + (threadIdx.x >> 6);
    o = __builtin_amdgcn_readfirstlane(o);
    const int*   ip = idx + o * KOUT;
    const float* wp = w   + o * KOUT;

    float ax = 0.f, ay = 0.f;
    #pragma unroll
    for (int k = 0; k < KOUT; ++k) {
        int   j  = __builtin_amdgcn_readfirstlane(ip[k]);
        float wk = wp[k];
        unsigned u = actu[(unsigned)j * 64 + lane];
        ax = fmaf(wk, bf_lo(u), ax);
        ay = fmaf(wk, bf_hi(u), ay);
    }
    out[(2 * lane + 0) * OUTN + o] = 1.f / (1.f + __expf(-SCALEA * ax));
    out[(2 * lane + 1) * OUTN + o] = 1.f / (1.f + __expf(-SCALEA * ay));
}

extern "C" void kernel_launch(void* const* d_in, const int* in_sizes, int n_in,
                              void* d_out, int out_size, void* d_ws, size_t ws_size,
                              hipStream_t stream) {
    // setup_inputs() order: x, w_hidden, w_out, idx_hidden, idx_out
    const float* x          = (const float*)d_in[0];
    const float* w_hidden   = (const float*)d_in[1];
    const float* w_out      = (const float*)d_in[2];
    const int*   idx_hidden = (const int*)  d_in[3];
    const int*   idx_out    = (const int*)  d_in[4];
    float* out = (float*)d_out;

    // Activation buffer: (4096 + 262144) nodes x 128 batch x 2B bf16 = 68.2 MB
    unsigned* actu = (unsigned*)d_ws;

    transpose_x<<<NUM_IN / 64, 256, 0, stream>>>(x, actu);

    for (int l = 0; l < LVL; ++l) {
        hidden_level<<<HID / 4, 256, 0, stream>>>(
            actu,
            idx_hidden + (size_t)l * HID * KH,
            w_hidden   + (size_t)l * HID * KH,
            NUM_IN + l * HID);
    }

    output_layer<<<OUTN / 4, 256, 0, stream>>>(actu, idx_out, w_out, out);
}